// Round 8
// baseline (84.033 us; speedup 1.0000x reference)
//
#include <hip/hip_runtime.h>
#include <hip/hip_bf16.h>
#include <cstdint>
#include <cstddef>

typedef float  f32x4  __attribute__((ext_vector_type(4)));
typedef __bf16 bf16x8 __attribute__((ext_vector_type(8)));
typedef __bf16 bf16x4 __attribute__((ext_vector_type(4)));

#define MFMA(a, b, c) __builtin_amdgcn_mfma_f32_16x16x32_bf16((a), (b), (c), 0, 0, 0)

#define B_     8
#define S_     2048
#define D_     1024
#define E_     64
#define YSZ    (B_ * S_ * D_)   // 16777216
#define KTR    16               // truncation depth: rho^16 ~ 2e-7

// Fragment-permuted B layouts (validated R7):
//   frag block f, lane l, elem j <-> B[k][n], n = tile*16 + (l&15), k = 32blk*32 + (l>>4)*8 + j
//   load = base + fragblock*512 + lane*8  (one coalesced 1KB instruction)

// ---------------- k_su: permuted weight conversions only ----------------
__global__ __launch_bounds__(256) void k_su(const float* __restrict__ w_in,
                                            const float* __restrict__ w_out,
                                            __bf16* __restrict__ winbF,
                                            __bf16* __restrict__ wobF) {
  const int i = blockIdx.x * 256 + threadIdx.x;
  {
    // w_in[e][k] -> winbF frag((k>>5)*4 + (e>>4))
    const int e = i >> 10, k = i & 1023;
    const int dst = ((k >> 5) * 4 + (e >> 4)) * 512 + ((k >> 3) & 3) * 128 + (e & 15) * 8 + (k & 7);
    winbF[dst] = (__bf16)w_in[i];
  }
  {
    // w_out[d][e] -> wobF frag((d>>4)*2 + (e>>5))
    const int d = i >> 6, e = i & 63;
    const int dst = ((d >> 4) * 2 + (e >> 5)) * 512 + ((e >> 3) & 3) * 128 + (d & 15) * 8 + (e & 7);
    wobF[dst] = (__bf16)w_out[i];
  }
}

// ---------------- k_b: beta GEMM (blocks 0..255) || impulse (blocks 256..259) ----------------
// Beta: block = 64 rows x 64 e, K=1024 in 8 steps of 128. x staged f32->bf16 into
// dbuf LDS [2][64][136] (pad -> 2-way-free banks), issue-early/write-late (T14).
// Wave w = rows w*16..+15, all 4 e-tiles: 16 MFMA/step, acc[4]. 1 barrier/step.
__global__ __launch_bounds__(256) void k_b(const float* __restrict__ x,
                                           const __bf16* __restrict__ winbF,
                                           const float* __restrict__ resonance,
                                           const float* __restrict__ alpha,
                                           const float* __restrict__ omega,
                                           __bf16* __restrict__ beta_bf,
                                           __bf16* __restrict__ GtF,
                                           float* __restrict__ CkTR,
                                           float* __restrict__ CkTI) {
  __shared__ __bf16 lsA[2][64][136];
  __shared__ __bf16 lsr[16][72];
  __shared__ __bf16 lsi[16][72];

  const int tid = threadIdx.x;

  if (blockIdx.x < 256) {
    const int w = tid >> 6, lane = tid & 63;
    const int u = lane >> 4, fl = lane & 15;
    const int rowbase = blockIdx.x * 64;

    // staging map: thread -> (row = tid>>2, 32 cols at (tid&3)*32)
    const int srow = tid >> 2, scb = (tid & 3) * 32;
    const float* xs = x + (size_t)(rowbase + srow) * 1024 + scb;

    f32x4 pf[8];
    // prologue: stage step 0
#pragma unroll
    for (int q = 0; q < 8; q++) pf[q] = *(const f32x4*)(xs + q * 4);
#pragma unroll
    for (int q = 0; q < 4; q++) {
      bf16x8 v;
#pragma unroll
      for (int j = 0; j < 4; j++) { v[j] = (__bf16)pf[2 * q][j]; v[j + 4] = (__bf16)pf[2 * q + 1][j]; }
      *(bf16x8*)&lsA[0][srow][scb + q * 8] = v;
    }
    __syncthreads();

    f32x4 acc[4] = {};
    int cur = 0;

#pragma unroll
    for (int kk = 0; kk < 8; kk++) {
      if (kk < 7) {   // issue next-step global loads early (hide under MFMA)
#pragma unroll
        for (int q = 0; q < 8; q++) pf[q] = *(const f32x4*)(xs + (kk + 1) * 128 + q * 4);
      }
      // compute on buffer `cur`: 4 k-blocks x 4 e-tiles
#pragma unroll
      for (int kb = 0; kb < 4; kb++) {
        const bf16x8 a = *(const bf16x8*)&lsA[cur][w * 16 + fl][kb * 32 + u * 8];
#pragma unroll
        for (int et = 0; et < 4; et++) {
          const bf16x8 b = *(const bf16x8*)(winbF + (size_t)((kk * 4 + kb) * 4 + et) * 512 + lane * 8);
          acc[et] = MFMA(a, b, acc[et]);
        }
      }
      if (kk < 7) {   // write-late into the other buffer, one barrier/step
#pragma unroll
        for (int q = 0; q < 4; q++) {
          bf16x8 v;
#pragma unroll
          for (int j = 0; j < 4; j++) { v[j] = (__bf16)pf[2 * q][j]; v[j + 4] = (__bf16)pf[2 * q + 1][j]; }
          *(bf16x8*)&lsA[cur ^ 1][srow][scb + q * 8] = v;
        }
        __syncthreads();
        cur ^= 1;
      }
    }

#pragma unroll
    for (int et = 0; et < 4; et++)
#pragma unroll
      for (int r = 0; r < 4; r++)
        beta_bf[(size_t)(rowbase + w * 16 + u * 4 + r) * 64 + et * 16 + fl] = (__bf16)acc[et][r];
    return;
  }

  // ---- impulse: C_k = R(LambdaR)^k; one wave, 16 impulse columns per block ----
  if (tid >= 64) return;
  const int lane = tid;
  const int u = lane >> 4, fl = lane & 15;
  const int ecol = (blockIdx.x - 256) * 16 + fl;

  bf16x8 afr[4][2];   // A[f][e] = R[e][f] - (e==f)
#pragma unroll
  for (int mt = 0; mt < 4; mt++)
#pragma unroll
    for (int kt = 0; kt < 2; kt++)
#pragma unroll
      for (int j = 0; j < 8; j++) {
        const int e = kt * 32 + u * 8 + j;
        const int f = mt * 16 + fl;
        float v = resonance[e * 64 + f];
        if (e == f) v -= 1.0f;
        afr[mt][kt][j] = (__bf16)v;
      }

  float mcv[4][4], msv[4][4];
#pragma unroll
  for (int mt = 0; mt < 4; mt++)
#pragma unroll
    for (int r = 0; r < 4; r++) {
      const int fr = mt * 16 + u * 4 + r;
      const float mg = 1.0f / (1.0f + expf(-alpha[fr]));
      mcv[mt][r] = mg * cosf(omega[fr]);
      msv[mt][r] = mg * sinf(omega[fr]);
    }

  f32x4 sr[4] = {}, si[4] = {};

  for (int s = 0; s < KTR; s++) {
    f32x4 rr[4], ri[4];
#pragma unroll
    for (int mt = 0; mt < 4; mt++)
#pragma unroll
      for (int r = 0; r < 4; r++) {
        const float bt = (s == 0 && (mt * 16 + u * 4 + r) == ecol) ? 1.0f : 0.0f;
        rr[mt][r] = mcv[mt][r] * sr[mt][r] - msv[mt][r] * si[mt][r] + bt;
        ri[mt][r] = msv[mt][r] * sr[mt][r] + mcv[mt][r] * si[mt][r];
      }
#pragma unroll
    for (int mt = 0; mt < 4; mt++) {
      bf16x4 pr, pi;
#pragma unroll
      for (int r = 0; r < 4; r++) { pr[r] = (__bf16)rr[mt][r]; pi[r] = (__bf16)ri[mt][r]; }
      *(bf16x4*)&lsr[fl][mt * 16 + u * 4] = pr;
      *(bf16x4*)&lsi[fl][mt * 16 + u * 4] = pi;
    }
    // single wave: compiler lgkmcnt orders ds_write -> ds_read; no barrier needed
    bf16x8 brf[2], bif[2];
#pragma unroll
    for (int kt = 0; kt < 2; kt++) {
      brf[kt] = *(const bf16x8*)&lsr[fl][kt * 32 + u * 8];
      bif[kt] = *(const bf16x8*)&lsi[fl][kt * 32 + u * 8];
    }
#pragma unroll
    for (int mt = 0; mt < 4; mt++) {
      f32x4 dr = MFMA(afr[mt][0], brf[0], rr[mt]);
      sr[mt]   = MFMA(afr[mt][1], brf[1], dr);
      f32x4 di = MFMA(afr[mt][0], bif[0], ri[mt]);
      si[mt]   = MFMA(afr[mt][1], bif[1], di);
    }
    // state now equals C_s: store GtF (conv frag layout) + CkT ([k][e][f], fin)
#pragma unroll
    for (int mt = 0; mt < 4; mt++)
#pragma unroll
      for (int r = 0; r < 4; r++) {
        const int f = mt * 16 + u * 4 + r;
        GtF[((s * 2 + (ecol >> 5)) * 4 + mt) * 512 + ((ecol >> 3) & 3) * 128 + (u * 4 + r) * 8 + (ecol & 7)]
            = (__bf16)sr[mt][r];
        CkTR[s * 4096 + ecol * 64 + f] = sr[mt][r];
        CkTI[s * 4096 + ecol * 64 + f] = si[mt][r];
      }
  }
}

// ---------------- k_cfy: conv + y GEMM + LN (blocks 0..1023) || fin (1024..1031) ----------------
// Block = 16 seq rows x full D=1024, 4 waves; ~4 independent blocks/CU.
// Phase A: wave w = f-tile w; 16 lags, A from padded halo LDS, B frag-coalesced GtF.
// Phase B: wave w = d-quarter; acc[16] (proven spill-free shape); LN across 4 waves.
__global__ __launch_bounds__(256) void k_cfy(const __bf16* __restrict__ beta_bf,
                                             const __bf16* __restrict__ GtF,
                                             const __bf16* __restrict__ wobF,
                                             const float* __restrict__ gamma,
                                             const float* __restrict__ lbeta,
                                             const float* __restrict__ CkTR,
                                             const float* __restrict__ CkTI,
                                             float* __restrict__ y) {
  __shared__ __bf16 halo[32][72];
  __shared__ __bf16 st[16][72];
  __shared__ float pS1[4][16];
  __shared__ float pS2[4][16];

  const int tid = threadIdx.x;
  const int w = tid >> 6, lane = tid & 63;
  const int u = lane >> 4, fl = lane & 15;

  if (blockIdx.x >= 1024) {
    // ---- fin: r_fin/i_fin = sum_k beta[2047-k] @ C_k ----
    if (tid >= 64) return;
    const int b = blockIdx.x - 1024;
    const int f = tid;
    float aR = 0.f, aI = 0.f;
#pragma unroll
    for (int k = 0; k < KTR; k++) {
      const __bf16* br = beta_bf + (size_t)(b * S_ + (S_ - 1) - k) * 64;
      const float* cR = CkTR + k * 4096 + f;
      const float* cI = CkTI + k * 4096 + f;
#pragma unroll
      for (int e = 0; e < 64; e++) {
        const float bv = (float)br[e];   // wave-uniform -> broadcast
        aR += bv * cR[e * 64];           // lanes f contiguous -> coalesced
        aI += bv * cI[e * 64];
      }
    }
    y[YSZ + b * 64 + f]       = aR;
    y[YSZ + 512 + b * 64 + f] = aI;
    return;
  }

  const int rowbase = blockIdx.x * 16;
  const int tloc = rowbase & (S_ - 1);

  // ---- stage beta halo rows rowbase-16 .. rowbase+15 (zero before batch start) ----
  {
    const int hr = tid >> 3, hc = (tid & 7) * 8;
    bf16x8 v = {};
    if (tloc - 16 + hr >= 0)
      v = *(const bf16x8*)(beta_bf + (size_t)(rowbase - 16 + hr) * 64 + hc);
    *(bf16x8*)&halo[hr][hc] = v;
  }
  __syncthreads();

  // ---- phase A: conv over 16 lags; wave w = f-tile ----
  {
    f32x4 acc1 = {};
#pragma unroll
    for (int k = 0; k < KTR; k++) {
      const int arow = 16 + fl - k;
      const bf16x8 a0 = *(const bf16x8*)&halo[arow][u * 8];
      const bf16x8 a1 = *(const bf16x8*)&halo[arow][32 + u * 8];
      const bf16x8 b0 = *(const bf16x8*)(GtF + (size_t)((k * 2 + 0) * 4 + w) * 512 + lane * 8);
      const bf16x8 b1 = *(const bf16x8*)(GtF + (size_t)((k * 2 + 1) * 4 + w) * 512 + lane * 8);
      acc1 = MFMA(a0, b0, acc1);
      acc1 = MFMA(a1, b1, acc1);
    }
#pragma unroll
    for (int r = 0; r < 4; r++)
      st[u * 4 + r][w * 16 + fl] = (__bf16)acc1[r];
  }
  __syncthreads();

  // ---- phase B: y = st @ w_out^T + LN; wave w = d-quarter ----
  const bf16x8 ar0 = *(const bf16x8*)&st[fl][u * 8];
  const bf16x8 ar1 = *(const bf16x8*)&st[fl][32 + u * 8];

  f32x4 acc[16] = {};
#pragma unroll
  for (int ct = 0; ct < 16; ct++) {
    const bf16x8 b0 = *(const bf16x8*)(wobF + (size_t)(((w * 16 + ct) * 2 + 0) * 64 + lane) * 8);
    const bf16x8 b1 = *(const bf16x8*)(wobF + (size_t)(((w * 16 + ct) * 2 + 1) * 64 + lane) * 8);
    acc[ct] = MFMA(ar0, b0, acc[ct]);
    acc[ct] = MFMA(ar1, b1, acc[ct]);
  }

  float s1[4], s2[4];
#pragma unroll
  for (int r = 0; r < 4; r++) {
    float a = 0.f, q = 0.f;
#pragma unroll
    for (int ct = 0; ct < 16; ct++) {
      const float v = acc[ct][r];
      a += v; q += v * v;
    }
    s1[r] = a; s2[r] = q;
  }
#pragma unroll
  for (int m = 1; m < 16; m <<= 1) {
#pragma unroll
    for (int r = 0; r < 4; r++) {
      s1[r] += __shfl_xor(s1[r], m, 64);
      s2[r] += __shfl_xor(s2[r], m, 64);
    }
  }
  if (fl == 0) {
#pragma unroll
    for (int r = 0; r < 4; r++) {
      pS1[w][u * 4 + r] = s1[r];
      pS2[w][u * 4 + r] = s2[r];
    }
  }
  __syncthreads();

  float mu[4], rs[4];
#pragma unroll
  for (int r = 0; r < 4; r++) {
    const int rl = u * 4 + r;
    const float S1 = pS1[0][rl] + pS1[1][rl] + pS1[2][rl] + pS1[3][rl];
    const float S2 = pS2[0][rl] + pS2[1][rl] + pS2[2][rl] + pS2[3][rl];
    const float m  = S1 * (1.0f / 1024.0f);
    const float va = S2 * (1.0f / 1024.0f) - m * m;
    mu[r] = m;
    rs[r] = rsqrtf(va + 1e-5f);
  }

#pragma unroll
  for (int ct = 0; ct < 16; ct++) {
    const int d = w * 256 + ct * 16 + fl;
    const float gv = gamma[d], bv = lbeta[d];
#pragma unroll
    for (int r = 0; r < 4; r++) {
      const float v = (acc[ct][r] - mu[r]) * rs[r] * gv + bv;
      y[(size_t)(rowbase + u * 4 + r) * 1024 + d] = v;
    }
  }
}

extern "C" void kernel_launch(void* const* d_in, const int* in_sizes, int n_in,
                              void* d_out, int out_size, void* d_ws, size_t ws_size,
                              hipStream_t stream) {
  const float* x         = (const float*)d_in[0];
  const float* alpha     = (const float*)d_in[1];
  const float* omega     = (const float*)d_in[2];
  const float* w_in      = (const float*)d_in[3];
  const float* w_out     = (const float*)d_in[4];
  const float* resonance = (const float*)d_in[5];
  const float* ln_g      = (const float*)d_in[6];
  const float* ln_b      = (const float*)d_in[7];
  float* out = (float*)d_out;

  char* ws = (char*)d_ws;
  __bf16* beta_bf = (__bf16*)ws;                                   // 2 MB
  __bf16* winbF   = (__bf16*)(ws + (2u << 20));                    // 128 KB
  __bf16* wobF    = (__bf16*)(ws + (2u << 20) + (128u << 10));     // 128 KB
  __bf16* GtF     = (__bf16*)(ws + (2u << 20) + (256u << 10));     // 128 KB
  float*  CkTR    = (float*) (ws + (2u << 20) + (384u << 10));     // 256 KB
  float*  CkTI    = (float*) (ws + (2u << 20) + (640u << 10));     // 256 KB

  k_su  <<<256,  256, 0, stream>>>(w_in, w_out, winbF, wobF);
  k_b   <<<260,  256, 0, stream>>>(x, winbF, resonance, alpha, omega,
                                   beta_bf, GtF, CkTR, CkTI);
  k_cfy <<<1032, 256, 0, stream>>>(beta_bf, GtF, wobF, ln_g, ln_b, CkTR, CkTI, out);
}

// Round 9
// 74.657 us; speedup vs baseline: 1.1256x; 1.1256x over previous
//
#include <hip/hip_runtime.h>
#include <hip/hip_bf16.h>
#include <cstdint>
#include <cstddef>

typedef float  f32x4  __attribute__((ext_vector_type(4)));
typedef __bf16 bf16x8 __attribute__((ext_vector_type(8)));
typedef __bf16 bf16x4 __attribute__((ext_vector_type(4)));

#define MFMA(a, b, c) __builtin_amdgcn_mfma_f32_16x16x32_bf16((a), (b), (c), 0, 0, 0)

#define B_     8
#define S_     2048
#define D_     1024
#define E_     64
#define YSZ    (B_ * S_ * D_)   // 16777216
#define KTR    16               // truncation depth: rho^16 ~ 2e-7

// Fragment-permuted layouts (B-operand of mfma_f32_16x16x32_bf16) [validated R7]:
//   frag(tile, kt) lane l elem j  <->  B[k][n], n = tile*16 + (l&15), k = kt*32 + (l>>4)*8 + j
// so a wave's fragment load is base + l*16B : one coalesced 1KB instruction.

// ---------------- k_su: permuted weight conversion (blocks 0..255) || impulse (256..259) ----------------
__global__ __launch_bounds__(256) void k_su(const float* __restrict__ w_in,
                                            const float* __restrict__ w_out,
                                            const float* __restrict__ resonance,
                                            const float* __restrict__ alpha,
                                            const float* __restrict__ omega,
                                            __bf16* __restrict__ winbF,
                                            __bf16* __restrict__ wobF,
                                            __bf16* __restrict__ GtF,
                                            float* __restrict__ CkTR,
                                            float* __restrict__ CkTI) {
  __shared__ __bf16 lsr[16][72];
  __shared__ __bf16 lsi[16][72];

  const int tid = threadIdx.x;

  if (blockIdx.x < 256) {
    const int i = blockIdx.x * 256 + tid;
    {
      // w_in[e][k] -> winbF frag(q = e>>4, kt = (k>>5)&1) at K-step kk = k>>6
      const int e = i >> 10, k = i & 1023;
      const int dst = ((k >> 5) * 4 + (e >> 4)) * 512 + ((k >> 3) & 3) * 128 + (e & 15) * 8 + (k & 7);
      winbF[dst] = (__bf16)w_in[i];
    }
    {
      // w_out[d][e] -> wobF frag(ct-tile d>>4, kt = e>>5)
      const int d = i >> 6, e = i & 63;
      const int dst = ((d >> 4) * 2 + (e >> 5)) * 512 + ((e >> 3) & 3) * 128 + (d & 15) * 8 + (e & 7);
      wobF[dst] = (__bf16)w_out[i];
    }
    return;
  }

  // ---- impulse: C_k = R(LambdaR)^k; one wave, 16 impulse columns per block ----
  if (tid >= 64) return;
  const int lane = tid;
  const int u = lane >> 4, fl = lane & 15;
  const int ecol = (blockIdx.x - 256) * 16 + fl;

  bf16x8 afr[4][2];   // A[f][e] = R[e][f] - (e==f)
#pragma unroll
  for (int mt = 0; mt < 4; mt++)
#pragma unroll
    for (int kt = 0; kt < 2; kt++)
#pragma unroll
      for (int j = 0; j < 8; j++) {
        const int e = kt * 32 + u * 8 + j;
        const int f = mt * 16 + fl;
        float v = resonance[e * 64 + f];
        if (e == f) v -= 1.0f;
        afr[mt][kt][j] = (__bf16)v;
      }

  float mcv[4][4], msv[4][4];
#pragma unroll
  for (int mt = 0; mt < 4; mt++)
#pragma unroll
    for (int r = 0; r < 4; r++) {
      const int fr = mt * 16 + u * 4 + r;
      const float mg = 1.0f / (1.0f + expf(-alpha[fr]));
      mcv[mt][r] = mg * cosf(omega[fr]);
      msv[mt][r] = mg * sinf(omega[fr]);
    }

  f32x4 sr[4] = {}, si[4] = {};

  for (int s = 0; s < KTR; s++) {
    f32x4 rr[4], ri[4];
#pragma unroll
    for (int mt = 0; mt < 4; mt++)
#pragma unroll
      for (int r = 0; r < 4; r++) {
        const float bt = (s == 0 && (mt * 16 + u * 4 + r) == ecol) ? 1.0f : 0.0f;
        rr[mt][r] = mcv[mt][r] * sr[mt][r] - msv[mt][r] * si[mt][r] + bt;
        ri[mt][r] = msv[mt][r] * sr[mt][r] + mcv[mt][r] * si[mt][r];
      }
#pragma unroll
    for (int mt = 0; mt < 4; mt++) {
      bf16x4 pr, pi;
#pragma unroll
      for (int r = 0; r < 4; r++) { pr[r] = (__bf16)rr[mt][r]; pi[r] = (__bf16)ri[mt][r]; }
      *(bf16x4*)&lsr[fl][mt * 16 + u * 4] = pr;
      *(bf16x4*)&lsi[fl][mt * 16 + u * 4] = pi;
    }
    // single wave: compiler lgkmcnt orders ds_write -> ds_read; no barrier needed
    bf16x8 brf[2], bif[2];
#pragma unroll
    for (int kt = 0; kt < 2; kt++) {
      brf[kt] = *(const bf16x8*)&lsr[fl][kt * 32 + u * 8];
      bif[kt] = *(const bf16x8*)&lsi[fl][kt * 32 + u * 8];
    }
#pragma unroll
    for (int mt = 0; mt < 4; mt++) {
      f32x4 dr = MFMA(afr[mt][0], brf[0], rr[mt]);
      sr[mt]   = MFMA(afr[mt][1], brf[1], dr);
      f32x4 di = MFMA(afr[mt][0], bif[0], ri[mt]);
      si[mt]   = MFMA(afr[mt][1], bif[1], di);
    }
    // state now equals C_s: store GtF (conv frag layout) + CkT ([k][e][f], fin)
#pragma unroll
    for (int mt = 0; mt < 4; mt++)
#pragma unroll
      for (int r = 0; r < 4; r++) {
        const int f = mt * 16 + u * 4 + r;
        GtF[((s * 2 + (ecol >> 5)) * 4 + mt) * 512 + ((ecol >> 3) & 3) * 128 + (u * 4 + r) * 8 + (ecol & 7)]
            = (__bf16)sr[mt][r];
        CkTR[s * 4096 + ecol * 64 + f] = sr[mt][r];
        CkTI[s * 4096 + ecol * 64 + f] = si[mt][r];
      }
  }
}

// ---------------- k_b: beta_bf = bf16(x @ w_in^T), LDS-staged A, frag-coalesced B [R7 verbatim] ----------------
__global__ __launch_bounds__(256) void k_b(const float* __restrict__ x,
                                           const __bf16* __restrict__ winbF,
                                           __bf16* __restrict__ beta_bf) {
  __shared__ __bf16 lsA[2][32][72];

  const int tid = threadIdx.x;
  const int w = tid >> 6, lane = tid & 63;
  const int u = lane >> 4, fl = lane & 15;
  const int rt = w & 1, eh = w >> 1;
  const int rowbase = blockIdx.x * 32;

  const int srow = tid >> 3, scol = (tid & 7) * 8;
  const float* xs = x + (size_t)(rowbase + srow) * 1024 + scol;

  // prologue: stage step 0
  {
    const f32x4 c0 = *(const f32x4*)(xs);
    const f32x4 c1 = *(const f32x4*)(xs + 4);
    bf16x8 v;
#pragma unroll
    for (int j = 0; j < 4; j++) { v[j] = (__bf16)c0[j]; v[j + 4] = (__bf16)c1[j]; }
    *(bf16x8*)&lsA[0][srow][scol] = v;
  }
  __syncthreads();

  f32x4 acc[2] = {};
  int cur = 0;

#pragma unroll
  for (int kk = 0; kk < 16; kk++) {
    f32x4 n0, n1;
    if (kk < 15) {                       // issue next-step staging loads early
      n0 = *(const f32x4*)(xs + (kk + 1) * 64);
      n1 = *(const f32x4*)(xs + (kk + 1) * 64 + 4);
    }
    // B fragments: coalesced 1KB loads from winbF (L2-hot)
    bf16x8 b[2][2];
#pragma unroll
    for (int et = 0; et < 2; et++)
#pragma unroll
      for (int kt = 0; kt < 2; kt++)
        b[et][kt] = *(const bf16x8*)(winbF +
            (size_t)(((kk * 2 + kt) * 4 + eh * 2 + et) * 64 + lane) * 8);
    // A fragments from LDS (pad-72: 2-way bank aliasing, free)
    const bf16x8 a0 = *(const bf16x8*)&lsA[cur][rt * 16 + fl][u * 8];
    const bf16x8 a1 = *(const bf16x8*)&lsA[cur][rt * 16 + fl][32 + u * 8];
#pragma unroll
    for (int et = 0; et < 2; et++) {
      acc[et] = MFMA(a0, b[et][0], acc[et]);
      acc[et] = MFMA(a1, b[et][1], acc[et]);
    }
    if (kk < 15) {
      bf16x8 v;
#pragma unroll
      for (int j = 0; j < 4; j++) { v[j] = (__bf16)n0[j]; v[j + 4] = (__bf16)n1[j]; }
      *(bf16x8*)&lsA[cur ^ 1][srow][scol] = v;   // write other buffer
      __syncthreads();                           // one barrier per step (dbuf)
      cur ^= 1;
    }
  }

#pragma unroll
  for (int et = 0; et < 2; et++)
#pragma unroll
    for (int r = 0; r < 4; r++)
      beta_bf[(size_t)(rowbase + rt * 16 + u * 4 + r) * 64 + eh * 32 + et * 16 + fl]
          = (__bf16)acc[et][r];
}

// ---------------- k_cfy: conv + y GEMM + LN + WIDE-STORE epilogue || fin ----------------
// R7 structure (512 main blocks x 512 thr, 32 rows x 1024 d) with one change:
// the y write goes through a small LDS transpose (4 ct-chunks) so every global
// store is a row-contiguous f32x4 (1KB/wave-instr) instead of 64 scalar stores.
__global__ __launch_bounds__(512) void k_cfy(const __bf16* __restrict__ beta_bf,
                                             const __bf16* __restrict__ GtF,
                                             const __bf16* __restrict__ wobF,
                                             const float* __restrict__ gamma,
                                             const float* __restrict__ lbeta,
                                             const float* __restrict__ CkTR,
                                             const float* __restrict__ CkTI,
                                             float* __restrict__ y) {
  __shared__ __bf16 halo[48][72];
  __shared__ __bf16 st[32][72];
  __shared__ float pS1[8][16];
  __shared__ float pS2[8][16];
  __shared__ float ldsY[4][32][68];   // [d-quarter][row][64 cols + pad]

  const int tid = threadIdx.x;
  const int w = tid >> 6, lane = tid & 63;
  const int u = lane >> 4, fl = lane & 15;

  if (blockIdx.x >= 512) {
    // ---- fin: r_fin/i_fin = sum_k beta[2047-k] @ C_k ----
    if (tid >= 64) return;
    const int b = blockIdx.x - 512;
    const int f = tid;
    float aR = 0.f, aI = 0.f;
#pragma unroll
    for (int k = 0; k < KTR; k++) {
      const __bf16* br = beta_bf + (size_t)(b * S_ + (S_ - 1) - k) * 64;
      const float* cR = CkTR + k * 4096 + f;
      const float* cI = CkTI + k * 4096 + f;
#pragma unroll
      for (int e = 0; e < 64; e++) {
        const float bv = (float)br[e];   // wave-uniform -> broadcast
        aR += bv * cR[e * 64];           // lanes f contiguous -> coalesced
        aI += bv * cI[e * 64];
      }
    }
    y[YSZ + b * 64 + f]       = aR;
    y[YSZ + 512 + b * 64 + f] = aI;
    return;
  }

  const int rowbase = blockIdx.x * 32;
  const int tloc = rowbase & (S_ - 1);

  // ---- stage beta halo: rows rowbase-16 .. rowbase+31, zeroed before batch start ----
  if (tid < 384) {
    const int hr = tid >> 3, hc = (tid & 7) * 8;
    bf16x8 v = {};
    if (tloc - 16 + hr >= 0)
      v = *(const bf16x8*)(beta_bf + (size_t)(rowbase - 16 + hr) * 64 + hc);
    *(bf16x8*)&halo[hr][hc] = v;
  }
  __syncthreads();

  const int rt = w >> 2;

  // ---- phase A: conv over 16 lags; B frags coalesced from GtF ----
  {
    const int fq = w & 3;
    f32x4 acc1 = {};
#pragma unroll
    for (int k = 0; k < KTR; k++) {
      const bf16x8 b0 = *(const bf16x8*)(GtF + (size_t)(((k * 2 + 0) * 4 + fq) * 64 + lane) * 8);
      const bf16x8 b1 = *(const bf16x8*)(GtF + (size_t)(((k * 2 + 1) * 4 + fq) * 64 + lane) * 8);
      const int hrow = 16 + rt * 16 + fl - k;
      const bf16x8 a0 = *(const bf16x8*)&halo[hrow][u * 8];
      const bf16x8 a1 = *(const bf16x8*)&halo[hrow][32 + u * 8];
      acc1 = MFMA(a0, b0, acc1);
      acc1 = MFMA(a1, b1, acc1);
    }
#pragma unroll
    for (int r = 0; r < 4; r++)
      st[rt * 16 + u * 4 + r][fq * 16 + fl] = (__bf16)acc1[r];
  }
  __syncthreads();

  // ---- phase B: y = st @ w_out^T + LN ----
  const int dq = w & 3;
  const bf16x8 ar0 = *(const bf16x8*)&st[rt * 16 + fl][u * 8];
  const bf16x8 ar1 = *(const bf16x8*)&st[rt * 16 + fl][32 + u * 8];

  f32x4 acc[16] = {};
#pragma unroll
  for (int ct = 0; ct < 16; ct++) {
    const bf16x8 b0 = *(const bf16x8*)(wobF + (size_t)((((dq * 16 + ct) * 2 + 0) * 64) + lane) * 8);
    const bf16x8 b1 = *(const bf16x8*)(wobF + (size_t)((((dq * 16 + ct) * 2 + 1) * 64) + lane) * 8);
    acc[ct] = MFMA(ar0, b0, acc[ct]);
    acc[ct] = MFMA(ar1, b1, acc[ct]);
  }

  // LN partials over this wave's 256 cols (rows rt*16 + u*4 + r)
  float s1[4], s2[4];
#pragma unroll
  for (int r = 0; r < 4; r++) {
    float a = 0.f, q = 0.f;
#pragma unroll
    for (int ct = 0; ct < 16; ct++) {
      const float v = acc[ct][r];
      a += v; q += v * v;
    }
    s1[r] = a; s2[r] = q;
  }
#pragma unroll
  for (int m = 1; m < 16; m <<= 1) {
#pragma unroll
    for (int r = 0; r < 4; r++) {
      s1[r] += __shfl_xor(s1[r], m, 64);
      s2[r] += __shfl_xor(s2[r], m, 64);
    }
  }
  if (fl == 0) {
#pragma unroll
    for (int r = 0; r < 4; r++) {
      pS1[w][u * 4 + r] = s1[r];
      pS2[w][u * 4 + r] = s2[r];
    }
  }
  __syncthreads();

  float mu[4], rs[4];
#pragma unroll
  for (int r = 0; r < 4; r++) {
    const int rl = u * 4 + r;
    float S1 = 0.f, S2 = 0.f;
#pragma unroll
    for (int g = 0; g < 4; g++) { S1 += pS1[rt * 4 + g][rl]; S2 += pS2[rt * 4 + g][rl]; }
    const float m  = S1 * (1.0f / 1024.0f);
    const float va = S2 * (1.0f / 1024.0f) - m * m;
    mu[r] = m;
    rs[r] = rsqrtf(va + 1e-5f);
  }

  // ---- wide-store epilogue: 4 ct-chunks through LDS, f32x4 coalesced stores ----
#pragma unroll
  for (int c = 0; c < 4; c++) {
#pragma unroll
    for (int q = 0; q < 4; q++) {            // ct = c*4 + q
      const int ct = c * 4 + q;
      const int d = dq * 256 + ct * 16 + fl;
      const float gv = gamma[d], bv = lbeta[d];
#pragma unroll
      for (int r = 0; r < 4; r++) {
        const float v = (acc[ct][r] - mu[r]) * rs[r] * gv + bv;
        ldsY[dq][rt * 16 + u * 4 + r][q * 16 + fl] = v;
      }
    }
    __syncthreads();
#pragma unroll
    for (int q2 = 0; q2 < 4; q2++) {
      const int gid = q2 * 512 + tid;        // 2048 f32x4 groups per chunk
      const int row = gid >> 6;              // 32 rows
      const int rem = gid & 63;
      const int strip = rem >> 4, cg = rem & 15;
      const f32x4 v = *(const f32x4*)&ldsY[strip][row][cg * 4];
      *(f32x4*)&y[(size_t)(rowbase + row) * 1024 + strip * 256 + c * 64 + cg * 4] = v;
    }
    __syncthreads();
  }
}

extern "C" void kernel_launch(void* const* d_in, const int* in_sizes, int n_in,
                              void* d_out, int out_size, void* d_ws, size_t ws_size,
                              hipStream_t stream) {
  const float* x         = (const float*)d_in[0];
  const float* alpha     = (const float*)d_in[1];
  const float* omega     = (const float*)d_in[2];
  const float* w_in      = (const float*)d_in[3];
  const float* w_out     = (const float*)d_in[4];
  const float* resonance = (const float*)d_in[5];
  const float* ln_g      = (const float*)d_in[6];
  const float* ln_b      = (const float*)d_in[7];
  float* out = (float*)d_out;

  char* ws = (char*)d_ws;
  __bf16* beta_bf = (__bf16*)ws;                                   // 2 MB
  __bf16* winbF   = (__bf16*)(ws + (2u << 20));                    // 128 KB
  __bf16* wobF    = (__bf16*)(ws + (2u << 20) + (128u << 10));     // 128 KB
  __bf16* GtF     = (__bf16*)(ws + (2u << 20) + (256u << 10));     // 128 KB
  float*  CkTR    = (float*) (ws + (2u << 20) + (384u << 10));     // 256 KB
  float*  CkTI    = (float*) (ws + (2u << 20) + (640u << 10));     // 256 KB

  k_su  <<<260, 256, 0, stream>>>(w_in, w_out, resonance, alpha, omega,
                                  winbF, wobF, GtF, CkTR, CkTI);
  k_b   <<<512, 256, 0, stream>>>(x, winbF, beta_bf);
  k_cfy <<<520, 512, 0, stream>>>(beta_bf, GtF, wobF, ln_g, ln_b, CkTR, CkTI, out);
}

// Round 10
// 62.239 us; speedup vs baseline: 1.3502x; 1.1995x over previous
//
#include <hip/hip_runtime.h>
#include <hip/hip_bf16.h>
#include <cstdint>
#include <cstddef>

typedef float  f32x4  __attribute__((ext_vector_type(4)));
typedef __bf16 bf16x8 __attribute__((ext_vector_type(8)));
typedef __bf16 bf16x4 __attribute__((ext_vector_type(4)));

#define MFMA(a, b, c) __builtin_amdgcn_mfma_f32_16x16x32_bf16((a), (b), (c), 0, 0, 0)

#define B_     8
#define S_     2048
#define D_     1024
#define E_     64
#define YSZ    (B_ * S_ * D_)   // 16777216
#define KTR    16               // truncation depth: rho^16 ~ 2e-7

// Fragment-permuted layouts (B-operand of mfma_f32_16x16x32_bf16) [validated R7]:
//   frag(tile, kt) lane l elem j  <->  B[k][n], n = tile*16 + (l&15), k = kt*32 + (l>>4)*8 + j
// so a wave's fragment load is base + l*16B : one coalesced 1KB instruction.

// ---------------- k_su: permuted weight conversion (blocks 0..255) || impulse (256..259) ----------------
__global__ __launch_bounds__(256) void k_su(const float* __restrict__ w_in,
                                            const float* __restrict__ w_out,
                                            const float* __restrict__ resonance,
                                            const float* __restrict__ alpha,
                                            const float* __restrict__ omega,
                                            __bf16* __restrict__ winbF,
                                            __bf16* __restrict__ wobF,
                                            __bf16* __restrict__ GtF,
                                            __bf16* __restrict__ CRF,
                                            __bf16* __restrict__ CIF) {
  __shared__ __bf16 lsr[16][72];
  __shared__ __bf16 lsi[16][72];

  const int tid = threadIdx.x;

  if (blockIdx.x < 256) {
    const int i = blockIdx.x * 256 + tid;
    {
      // w_in[e][k] -> winbF frag(q = e>>4, kt = (k>>5)&1) at K-step kk = k>>6
      const int e = i >> 10, k = i & 1023;
      const int dst = ((k >> 5) * 4 + (e >> 4)) * 512 + ((k >> 3) & 3) * 128 + (e & 15) * 8 + (k & 7);
      winbF[dst] = (__bf16)w_in[i];
    }
    {
      // w_out[d][e] -> wobF frag(ct-tile d>>4, kt = e>>5)
      const int d = i >> 6, e = i & 63;
      const int dst = ((d >> 4) * 2 + (e >> 5)) * 512 + ((e >> 3) & 3) * 128 + (d & 15) * 8 + (e & 7);
      wobF[dst] = (__bf16)w_out[i];
    }
    return;
  }

  // ---- impulse: C_k = R(LambdaR)^k; one wave, 16 impulse columns per block ----
  if (tid >= 64) return;
  const int lane = tid;
  const int u = lane >> 4, fl = lane & 15;
  const int ecol = (blockIdx.x - 256) * 16 + fl;

  bf16x8 afr[4][2];   // A[f][e] = R[e][f] - (e==f)
#pragma unroll
  for (int mt = 0; mt < 4; mt++)
#pragma unroll
    for (int kt = 0; kt < 2; kt++)
#pragma unroll
      for (int j = 0; j < 8; j++) {
        const int e = kt * 32 + u * 8 + j;
        const int f = mt * 16 + fl;
        float v = resonance[e * 64 + f];
        if (e == f) v -= 1.0f;
        afr[mt][kt][j] = (__bf16)v;
      }

  float mcv[4][4], msv[4][4];
#pragma unroll
  for (int mt = 0; mt < 4; mt++)
#pragma unroll
    for (int r = 0; r < 4; r++) {
      const int fr = mt * 16 + u * 4 + r;
      const float mg = 1.0f / (1.0f + expf(-alpha[fr]));
      mcv[mt][r] = mg * cosf(omega[fr]);
      msv[mt][r] = mg * sinf(omega[fr]);
    }

  f32x4 sr[4] = {}, si[4] = {};

  for (int s = 0; s < KTR; s++) {
    f32x4 rr[4], ri[4];
#pragma unroll
    for (int mt = 0; mt < 4; mt++)
#pragma unroll
      for (int r = 0; r < 4; r++) {
        const float bt = (s == 0 && (mt * 16 + u * 4 + r) == ecol) ? 1.0f : 0.0f;
        rr[mt][r] = mcv[mt][r] * sr[mt][r] - msv[mt][r] * si[mt][r] + bt;
        ri[mt][r] = msv[mt][r] * sr[mt][r] + mcv[mt][r] * si[mt][r];
      }
#pragma unroll
    for (int mt = 0; mt < 4; mt++) {
      bf16x4 pr, pi;
#pragma unroll
      for (int r = 0; r < 4; r++) { pr[r] = (__bf16)rr[mt][r]; pi[r] = (__bf16)ri[mt][r]; }
      *(bf16x4*)&lsr[fl][mt * 16 + u * 4] = pr;
      *(bf16x4*)&lsi[fl][mt * 16 + u * 4] = pi;
    }
    // single wave: compiler lgkmcnt orders ds_write -> ds_read; no barrier needed
    bf16x8 brf[2], bif[2];
#pragma unroll
    for (int kt = 0; kt < 2; kt++) {
      brf[kt] = *(const bf16x8*)&lsr[fl][kt * 32 + u * 8];
      bif[kt] = *(const bf16x8*)&lsi[fl][kt * 32 + u * 8];
    }
#pragma unroll
    for (int mt = 0; mt < 4; mt++) {
      f32x4 dr = MFMA(afr[mt][0], brf[0], rr[mt]);
      sr[mt]   = MFMA(afr[mt][1], brf[1], dr);
      f32x4 di = MFMA(afr[mt][0], bif[0], ri[mt]);
      si[mt]   = MFMA(afr[mt][1], bif[1], di);
    }
    // state now equals C_s: store GtF (conv frag layout) + CRF/CIF (fin frag layout,
    // K-index = s*64 + e  ->  k32 = s*2 + (e>>5), lane = ((e>>3)&3)*16 + (f&15), elem = e&7)
#pragma unroll
    for (int mt = 0; mt < 4; mt++)
#pragma unroll
      for (int r = 0; r < 4; r++) {
        GtF[((s * 2 + (ecol >> 5)) * 4 + mt) * 512 + ((ecol >> 3) & 3) * 128 + (u * 4 + r) * 8 + (ecol & 7)]
            = (__bf16)sr[mt][r];
        const int off = ((s * 2 + (ecol >> 5)) * 4 + mt) * 512 +
                        (((ecol >> 3) & 3) * 16 + u * 4 + r) * 8 + (ecol & 7);
        CRF[off] = (__bf16)sr[mt][r];
        CIF[off] = (__bf16)si[mt][r];
      }
  }
}

// ---------------- k_b: beta_bf = bf16(x @ w_in^T), LDS-staged A, frag-coalesced B [R7 verbatim] ----------------
__global__ __launch_bounds__(256) void k_b(const float* __restrict__ x,
                                           const __bf16* __restrict__ winbF,
                                           __bf16* __restrict__ beta_bf) {
  __shared__ __bf16 lsA[2][32][72];

  const int tid = threadIdx.x;
  const int w = tid >> 6, lane = tid & 63;
  const int u = lane >> 4, fl = lane & 15;
  const int rt = w & 1, eh = w >> 1;
  const int rowbase = blockIdx.x * 32;

  const int srow = tid >> 3, scol = (tid & 7) * 8;
  const float* xs = x + (size_t)(rowbase + srow) * 1024 + scol;

  // prologue: stage step 0
  {
    const f32x4 c0 = *(const f32x4*)(xs);
    const f32x4 c1 = *(const f32x4*)(xs + 4);
    bf16x8 v;
#pragma unroll
    for (int j = 0; j < 4; j++) { v[j] = (__bf16)c0[j]; v[j + 4] = (__bf16)c1[j]; }
    *(bf16x8*)&lsA[0][srow][scol] = v;
  }
  __syncthreads();

  f32x4 acc[2] = {};
  int cur = 0;

#pragma unroll
  for (int kk = 0; kk < 16; kk++) {
    f32x4 n0, n1;
    if (kk < 15) {                       // issue next-step staging loads early
      n0 = *(const f32x4*)(xs + (kk + 1) * 64);
      n1 = *(const f32x4*)(xs + (kk + 1) * 64 + 4);
    }
    // B fragments: coalesced 1KB loads from winbF (L2-hot)
    bf16x8 b[2][2];
#pragma unroll
    for (int et = 0; et < 2; et++)
#pragma unroll
      for (int kt = 0; kt < 2; kt++)
        b[et][kt] = *(const bf16x8*)(winbF +
            (size_t)(((kk * 2 + kt) * 4 + eh * 2 + et) * 64 + lane) * 8);
    // A fragments from LDS (pad-72: 2-way bank aliasing, free)
    const bf16x8 a0 = *(const bf16x8*)&lsA[cur][rt * 16 + fl][u * 8];
    const bf16x8 a1 = *(const bf16x8*)&lsA[cur][rt * 16 + fl][32 + u * 8];
#pragma unroll
    for (int et = 0; et < 2; et++) {
      acc[et] = MFMA(a0, b[et][0], acc[et]);
      acc[et] = MFMA(a1, b[et][1], acc[et]);
    }
    if (kk < 15) {
      bf16x8 v;
#pragma unroll
      for (int j = 0; j < 4; j++) { v[j] = (__bf16)n0[j]; v[j + 4] = (__bf16)n1[j]; }
      *(bf16x8*)&lsA[cur ^ 1][srow][scol] = v;   // write other buffer
      __syncthreads();                           // one barrier per step (dbuf)
      cur ^= 1;
    }
  }

#pragma unroll
  for (int et = 0; et < 2; et++)
#pragma unroll
    for (int r = 0; r < 4; r++)
      beta_bf[(size_t)(rowbase + rt * 16 + u * 4 + r) * 64 + eh * 32 + et * 16 + fl]
          = (__bf16)acc[et][r];
}

// ---------------- k_cfy: fin-as-MFMA (block 0) || conv + y GEMM + LN (blocks 1..512) ----------------
__global__ __launch_bounds__(512) void k_cfy(const __bf16* __restrict__ beta_bf,
                                             const __bf16* __restrict__ GtF,
                                             const __bf16* __restrict__ wobF,
                                             const float* __restrict__ gamma,
                                             const float* __restrict__ lbeta,
                                             const __bf16* __restrict__ CRF,
                                             const __bf16* __restrict__ CIF,
                                             float* __restrict__ y) {
  __shared__ __bf16 halo[48][72];
  __shared__ __bf16 st[32][72];
  __shared__ float pS1[8][16];
  __shared__ float pS2[8][16];
  __shared__ float ldsY[4][32][68];   // [d-quarter][row][64 cols + pad]

  const int tid = threadIdx.x;
  const int w = tid >> 6, lane = tid & 63;
  const int u = lane >> 4, fl = lane & 15;

  if (blockIdx.x == 0) {
    // ---- fin as 16x64x1024 MFMA GEMM: out[b][f] = sum_{k,e} beta[b][2047-k][e] * C_k[e][f]
    // A tile [16][1024] staged in LDS (rows 8..15 unused garbage, harmless: A-row r
    // only affects C-row r). Wave w: part = w>>1 (R/I), f-half = w&1 (2 f-tiles).
    __bf16 (*lsF)[1032] = (__bf16 (*)[1032])&ldsY[0][0][0];   // 16 x 1032 bf16 = 33KB, fits in ldsY
    if (tid < 512) {
#pragma unroll
      for (int it = 0; it < 2; it++) {
        const int t = it * 512 + tid;          // 1024 slots: seg = t>>3 (b,k), off = (t&7)*8
        const int seg = t >> 3, off = (t & 7) * 8;
        const int b = seg >> 4, k = seg & 15;
        const bf16x8 v = *(const bf16x8*)(beta_bf + (size_t)(b * S_ + (S_ - 1) - k) * 64 + off);
        *(bf16x8*)&lsF[b][k * 64 + off] = v;
      }
    }
    __syncthreads();

    const int part = w >> 1, fh = w & 1;
    const __bf16* CF = part ? CIF : CRF;
    f32x4 acc[2] = {};
#pragma unroll
    for (int k32 = 0; k32 < 32; k32++) {
      const bf16x8 a = *(const bf16x8*)&lsF[fl][k32 * 32 + u * 8];
#pragma unroll
      for (int ft = 0; ft < 2; ft++) {
        const bf16x8 b = *(const bf16x8*)(CF + (size_t)((k32 * 4 + fh * 2 + ft) * 64 + lane) * 8);
        acc[ft] = MFMA(a, b, acc[ft]);
      }
    }
    // C layout: row = u*4 + r (valid rows 0..7 -> u<2), col = ft*16 + fl
    if (u < 2) {
#pragma unroll
      for (int ft = 0; ft < 2; ft++)
#pragma unroll
        for (int r = 0; r < 4; r++) {
          const int b = u * 4 + r;
          const int f = fh * 32 + ft * 16 + fl;
          y[YSZ + part * 512 + b * 64 + f] = acc[ft][r];
        }
    }
    return;
  }

  const int rowbase = (blockIdx.x - 1) * 32;
  const int tloc = rowbase & (S_ - 1);

  // ---- stage beta halo: rows rowbase-16 .. rowbase+31, zeroed before batch start ----
  if (tid < 384) {
    const int hr = tid >> 3, hc = (tid & 7) * 8;
    bf16x8 v = {};
    if (tloc - 16 + hr >= 0)
      v = *(const bf16x8*)(beta_bf + (size_t)(rowbase - 16 + hr) * 64 + hc);
    *(bf16x8*)&halo[hr][hc] = v;
  }
  __syncthreads();

  const int rt = w >> 2;

  // ---- phase A: conv over 16 lags; B frags coalesced from GtF ----
  {
    const int fq = w & 3;
    f32x4 acc1 = {};
#pragma unroll
    for (int k = 0; k < KTR; k++) {
      const bf16x8 b0 = *(const bf16x8*)(GtF + (size_t)(((k * 2 + 0) * 4 + fq) * 64 + lane) * 8);
      const bf16x8 b1 = *(const bf16x8*)(GtF + (size_t)(((k * 2 + 1) * 4 + fq) * 64 + lane) * 8);
      const int hrow = 16 + rt * 16 + fl - k;
      const bf16x8 a0 = *(const bf16x8*)&halo[hrow][u * 8];
      const bf16x8 a1 = *(const bf16x8*)&halo[hrow][32 + u * 8];
      acc1 = MFMA(a0, b0, acc1);
      acc1 = MFMA(a1, b1, acc1);
    }
#pragma unroll
    for (int r = 0; r < 4; r++)
      st[rt * 16 + u * 4 + r][fq * 16 + fl] = (__bf16)acc1[r];
  }
  __syncthreads();

  // ---- phase B: y = st @ w_out^T + LN ----
  const int dq = w & 3;
  const bf16x8 ar0 = *(const bf16x8*)&st[rt * 16 + fl][u * 8];
  const bf16x8 ar1 = *(const bf16x8*)&st[rt * 16 + fl][32 + u * 8];

  f32x4 acc[16] = {};
#pragma unroll
  for (int ct = 0; ct < 16; ct++) {
    const bf16x8 b0 = *(const bf16x8*)(wobF + (size_t)((((dq * 16 + ct) * 2 + 0) * 64) + lane) * 8);
    const bf16x8 b1 = *(const bf16x8*)(wobF + (size_t)((((dq * 16 + ct) * 2 + 1) * 64) + lane) * 8);
    acc[ct] = MFMA(ar0, b0, acc[ct]);
    acc[ct] = MFMA(ar1, b1, acc[ct]);
  }

  // LN partials over this wave's 256 cols (rows rt*16 + u*4 + r)
  float s1[4], s2[4];
#pragma unroll
  for (int r = 0; r < 4; r++) {
    float a = 0.f, q = 0.f;
#pragma unroll
    for (int ct = 0; ct < 16; ct++) {
      const float v = acc[ct][r];
      a += v; q += v * v;
    }
    s1[r] = a; s2[r] = q;
  }
#pragma unroll
  for (int m = 1; m < 16; m <<= 1) {
#pragma unroll
    for (int r = 0; r < 4; r++) {
      s1[r] += __shfl_xor(s1[r], m, 64);
      s2[r] += __shfl_xor(s2[r], m, 64);
    }
  }
  if (fl == 0) {
#pragma unroll
    for (int r = 0; r < 4; r++) {
      pS1[w][u * 4 + r] = s1[r];
      pS2[w][u * 4 + r] = s2[r];
    }
  }
  __syncthreads();

  float mu[4], rs[4];
#pragma unroll
  for (int r = 0; r < 4; r++) {
    const int rl = u * 4 + r;
    float S1 = 0.f, S2 = 0.f;
#pragma unroll
    for (int g = 0; g < 4; g++) { S1 += pS1[rt * 4 + g][rl]; S2 += pS2[rt * 4 + g][rl]; }
    const float m  = S1 * (1.0f / 1024.0f);
    const float va = S2 * (1.0f / 1024.0f) - m * m;
    mu[r] = m;
    rs[r] = rsqrtf(va + 1e-5f);
  }

  // ---- wide-store epilogue: 4 ct-chunks through LDS, f32x4 coalesced stores ----
#pragma unroll
  for (int c = 0; c < 4; c++) {
#pragma unroll
    for (int q = 0; q < 4; q++) {            // ct = c*4 + q
      const int ct = c * 4 + q;
      const int d = dq * 256 + ct * 16 + fl;
      const float gv = gamma[d], bv = lbeta[d];
#pragma unroll
      for (int r = 0; r < 4; r++) {
        const float v = (acc[ct][r] - mu[r]) * rs[r] * gv + bv;
        ldsY[dq][rt * 16 + u * 4 + r][q * 16 + fl] = v;
      }
    }
    __syncthreads();
#pragma unroll
    for (int q2 = 0; q2 < 4; q2++) {
      const int gid = q2 * 512 + tid;        // 2048 f32x4 groups per chunk
      const int row = gid >> 6;              // 32 rows
      const int rem = gid & 63;
      const int strip = rem >> 4, cg = rem & 15;
      const f32x4 v = *(const f32x4*)&ldsY[strip][row][cg * 4];
      *(f32x4*)&y[(size_t)(rowbase + row) * 1024 + strip * 256 + c * 64 + cg * 4] = v;
    }
    __syncthreads();
  }
}

extern "C" void kernel_launch(void* const* d_in, const int* in_sizes, int n_in,
                              void* d_out, int out_size, void* d_ws, size_t ws_size,
                              hipStream_t stream) {
  const float* x         = (const float*)d_in[0];
  const float* alpha     = (const float*)d_in[1];
  const float* omega     = (const float*)d_in[2];
  const float* w_in      = (const float*)d_in[3];
  const float* w_out     = (const float*)d_in[4];
  const float* resonance = (const float*)d_in[5];
  const float* ln_g      = (const float*)d_in[6];
  const float* ln_b      = (const float*)d_in[7];
  float* out = (float*)d_out;

  char* ws = (char*)d_ws;
  __bf16* beta_bf = (__bf16*)ws;                                   // 2 MB
  __bf16* winbF   = (__bf16*)(ws + (2u << 20));                    // 128 KB
  __bf16* wobF    = (__bf16*)(ws + (2u << 20) + (128u << 10));     // 128 KB
  __bf16* GtF     = (__bf16*)(ws + (2u << 20) + (256u << 10));     // 128 KB
  __bf16* CRF     = (__bf16*)(ws + (2u << 20) + (384u << 10));     // 128 KB
  __bf16* CIF     = (__bf16*)(ws + (2u << 20) + (512u << 10));     // 128 KB

  k_su  <<<260, 256, 0, stream>>>(w_in, w_out, resonance, alpha, omega,
                                  winbF, wobF, GtF, CRF, CIF);
  k_b   <<<512, 256, 0, stream>>>(x, winbF, beta_bf);
  k_cfy <<<513, 512, 0, stream>>>(beta_bf, GtF, wobF, ln_g, ln_b, CRF, CIF, out);
}